// Round 1
// baseline (1845.026 us; speedup 1.0000x reference)
//
#include <hip/hip_runtime.h>

typedef float f4 __attribute__((ext_vector_type(4)));

#define HSTR 36            // padded batch stride in h_lds (32 used + 4 pad)
#define HL   (32 * HSTR)   // floats per layer in h_lds

// ws layout (floats)
#define WH_OFF  0          // 4096 f4 : [l][k][j] -> (i,f,g,o) columns of W_hh
#define WX_OFF  16384      // 3072 f4 : [l-1][k][j] of W_ih (layers 1..3)
#define WX0_OFF 28672      // 64 f4   : [k<2][j] of W_ih0
#define BS_OFF  28928      // 128 f4  : [l][j] bias quad (b_ih + b_hh)

__device__ __forceinline__ float fsig(float x) {
    float e = __builtin_amdgcn_exp2f(x * -1.4426950408889634f);
    return __builtin_amdgcn_rcpf(1.0f + e);
}
__device__ __forceinline__ float ftanh(float x) {
    float e = __builtin_amdgcn_exp2f(x * -2.8853900817779268f); // e^{-2x}
    return 2.0f * __builtin_amdgcn_rcpf(1.0f + e) - 1.0f;
}

__global__ void pack_weights(const float* __restrict__ Wih0, const float* __restrict__ Wih,
                             const float* __restrict__ Whh,  const float* __restrict__ bih,
                             const float* __restrict__ bhh,  float* __restrict__ ws) {
    int idx = blockIdx.x * 256 + threadIdx.x;
    f4* wH  = (f4*)(ws + WH_OFF);
    f4* wX  = (f4*)(ws + WX_OFF);
    f4* wX0 = (f4*)(ws + WX0_OFF);
    f4* bs  = (f4*)(ws + BS_OFF);
    if (idx < 4096) {
        int l = idx >> 10, k = (idx >> 5) & 31, j = idx & 31;
        const float* W = Whh + l * 4096;                      // (128,32) row-major
        f4 v = { W[j*32+k], W[(j+32)*32+k], W[(j+64)*32+k], W[(j+96)*32+k] };
        wH[idx] = v;
    } else if (idx < 7168) {
        int r = idx - 4096;
        int lm = r >> 10, k = (r >> 5) & 31, j = r & 31;
        const float* W = Wih + lm * 4096;
        f4 v = { W[j*32+k], W[(j+32)*32+k], W[(j+64)*32+k], W[(j+96)*32+k] };
        wX[r] = v;
    } else if (idx < 7232) {
        int r = idx - 7168;
        int k = r >> 5, j = r & 31;                           // W_ih0 is (128,2)
        f4 v = { Wih0[j*2+k], Wih0[(j+32)*2+k], Wih0[(j+64)*2+k], Wih0[(j+96)*2+k] };
        wX0[r] = v;
    } else if (idx < 7360) {
        int r = idx - 7232;
        int l = r >> 5, j = r & 31;
        const float* bi = bih + l * 128;
        const float* bh = bhh + l * 128;
        f4 v = { bi[j]+bh[j], bi[j+32]+bh[j+32], bi[j+64]+bh[j+64], bi[j+96]+bh[j+96] };
        bs[r] = v;
    }
}

// block = 256 threads = 8 batch-quads x 32 hidden units; each thread owns 4 batch rows
// of hidden unit j across all 4 layers. h is exchanged through LDS transposed [l][unit][batch].
__global__ __launch_bounds__(256, 2)
void lstm_fused(const float* __restrict__ xg, const float* __restrict__ ws,
                const float* __restrict__ Wlin, const float* __restrict__ blin,
                float* __restrict__ out) {
    __shared__ float h_lds[4 * HL] __attribute__((aligned(16)));

    const int tid = threadIdx.x;
    const int j   = tid & 31;        // hidden unit
    const int bq  = tid >> 5;        // batch quad 0..7
    const int b0  = blockIdx.x * 32 + bq * 4;

    const f4* wH  = (const f4*)(ws + WH_OFF);
    const f4* wX  = (const f4*)(ws + WX_OFF);
    const f4* wX0 = (const f4*)(ws + WX0_OFF);
    const f4* bs  = (const f4*)(ws + BS_OFF);

    // zero h state
    for (int i = tid; i < 4 * HL; i += 256) h_lds[i] = 0.0f;

    // preload per-thread constants
    f4 bias_r[4];
#pragma unroll
    for (int l = 0; l < 4; ++l) bias_r[l] = bs[l * 32 + j];
    const f4 wx00 = wX0[j];
    const f4 wx01 = wX0[32 + j];

    float c_st[4][4];
#pragma unroll
    for (int l = 0; l < 4; ++l)
#pragma unroll
        for (int bb = 0; bb < 4; ++bb) c_st[l][bb] = 0.0f;

    __syncthreads();

    f4 acc[4];
    float hn[4];

    for (int t = 0; t < 64; ++t) {
        // ---------------- layer 0: input = x[b][0..1][t] ----------------
#pragma unroll
        for (int bb = 0; bb < 4; ++bb) {
            float x0 = xg[(size_t)(b0 + bb) * 192 + t];
            float x1 = xg[(size_t)(b0 + bb) * 192 + 64 + t];
            acc[bb] = bias_r[0] + wx00 * x0 + wx01 * x1;
        }
#pragma unroll 8
        for (int k = 0; k < 32; ++k) {
            f4 w = wH[k * 32 + j];
            f4 a = *(const f4*)&h_lds[k * HSTR + bq * 4];
            acc[0] += w * a.x; acc[1] += w * a.y; acc[2] += w * a.z; acc[3] += w * a.w;
        }
#pragma unroll
        for (int bb = 0; bb < 4; ++bb) {
            float ig = fsig(acc[bb].x), fg = fsig(acc[bb].y);
            float gg = ftanh(acc[bb].z), og = fsig(acc[bb].w);
            float cn = fg * c_st[0][bb] + ig * gg;
            c_st[0][bb] = cn;
            hn[bb] = og * ftanh(cn);
        }
        __syncthreads();   // everyone done reading old h_lds[0]
        {
            f4 v = { hn[0], hn[1], hn[2], hn[3] };
            *(f4*)&h_lds[j * HSTR + bq * 4] = v;
        }
        __syncthreads();   // new h_lds[0] visible

        // ---------------- layers 1..3 ----------------
#pragma unroll
        for (int l = 1; l < 4; ++l) {
#pragma unroll
            for (int bb = 0; bb < 4; ++bb) acc[bb] = bias_r[l];
#pragma unroll 8
            for (int k = 0; k < 32; ++k) {   // input part: h of layer l-1 (this step)
                f4 w = wX[((l - 1) * 32 + k) * 32 + j];
                f4 a = *(const f4*)&h_lds[(l - 1) * HL + k * HSTR + bq * 4];
                acc[0] += w * a.x; acc[1] += w * a.y; acc[2] += w * a.z; acc[3] += w * a.w;
            }
#pragma unroll 8
            for (int k = 0; k < 32; ++k) {   // recurrent part: h of layer l (prev step)
                f4 w = wH[(l * 32 + k) * 32 + j];
                f4 a = *(const f4*)&h_lds[l * HL + k * HSTR + bq * 4];
                acc[0] += w * a.x; acc[1] += w * a.y; acc[2] += w * a.z; acc[3] += w * a.w;
            }
#pragma unroll
            for (int bb = 0; bb < 4; ++bb) {
                float ig = fsig(acc[bb].x), fg = fsig(acc[bb].y);
                float gg = ftanh(acc[bb].z), og = fsig(acc[bb].w);
                float cn = fg * c_st[l][bb] + ig * gg;
                c_st[l][bb] = cn;
                hn[bb] = og * ftanh(cn);
            }
            __syncthreads();
            {
                f4 v = { hn[0], hn[1], hn[2], hn[3] };
                *(f4*)&h_lds[l * HL + j * HSTR + bq * 4] = v;
            }
            __syncthreads();
        }
    }

    // ---------------- output head: sigmoid(h3 . W_lin + b_lin) ----------------
    if (tid < 32) {
        int bb = tid;
        float s = blin[0];
#pragma unroll
        for (int k = 0; k < 32; ++k)
            s += Wlin[k] * h_lds[3 * HL + k * HSTR + bb];
        out[blockIdx.x * 32 + bb] = fsig(s);
    }
}

extern "C" void kernel_launch(void* const* d_in, const int* in_sizes, int n_in,
                              void* d_out, int out_size, void* d_ws, size_t ws_size,
                              hipStream_t stream) {
    const float* x    = (const float*)d_in[0];
    const float* Wih0 = (const float*)d_in[1];
    const float* Wih  = (const float*)d_in[2];
    const float* Whh  = (const float*)d_in[3];
    const float* bih  = (const float*)d_in[4];
    const float* bhh  = (const float*)d_in[5];
    const float* Wlin = (const float*)d_in[6];
    const float* blin = (const float*)d_in[7];
    float* ws  = (float*)d_ws;
    float* out = (float*)d_out;

    pack_weights<<<29, 256, 0, stream>>>(Wih0, Wih, Whh, bih, bhh, ws);
    lstm_fused<<<512, 256, 0, stream>>>(x, ws, Wlin, blin, out);
}

// Round 2
// 1803.328 us; speedup vs baseline: 1.0231x; 1.0231x over previous
//
#include <hip/hip_runtime.h>

typedef float f4 __attribute__((ext_vector_type(4)));

// wave-local h buffer: [l][k][row8], row8 = bq*4+bb
#define HROW 8
#define HLAY (32 * HROW)     // 256 floats per layer

// ws layout (floats)
#define WH_OFF  0            // 4096 f4 : [l][k][j] -> (i,f,g,o) columns of W_hh
#define WX_OFF  16384        // 3072 f4 : [l-1][k][j] of W_ih (layers 1..3)
#define WX0_OFF 28672        // 64 f4   : [k<2][j] of W_ih0
#define BS_OFF  28928        // 128 f4  : [l][j] bias quad (b_ih + b_hh)

// Wait for this wave's outstanding LDS ops (h write -> h read ordering within the
// wave) WITHOUT draining vmcnt -- global weight loads stay in flight. The
// "memory" clobber stops the compiler hoisting the dependent ds_reads above it.
#define LGKM0() asm volatile("s_waitcnt lgkmcnt(0)" ::: "memory")

__device__ __forceinline__ float fsig(float x) {
    float e = __builtin_amdgcn_exp2f(x * -1.4426950408889634f);
    return __builtin_amdgcn_rcpf(1.0f + e);
}
__device__ __forceinline__ float ftanh(float x) {
    float e = __builtin_amdgcn_exp2f(x * -2.8853900817779268f); // e^{-2x}
    return 2.0f * __builtin_amdgcn_rcpf(1.0f + e) - 1.0f;
}

__global__ void pack_weights(const float* __restrict__ Wih0, const float* __restrict__ Wih,
                             const float* __restrict__ Whh,  const float* __restrict__ bih,
                             const float* __restrict__ bhh,  float* __restrict__ ws) {
    int idx = blockIdx.x * 256 + threadIdx.x;
    f4* wH  = (f4*)(ws + WH_OFF);
    f4* wX  = (f4*)(ws + WX_OFF);
    f4* wX0 = (f4*)(ws + WX0_OFF);
    f4* bs  = (f4*)(ws + BS_OFF);
    if (idx < 4096) {
        int l = idx >> 10, k = (idx >> 5) & 31, j = idx & 31;
        const float* W = Whh + l * 4096;                      // (128,32) row-major
        f4 v = { W[j*32+k], W[(j+32)*32+k], W[(j+64)*32+k], W[(j+96)*32+k] };
        wH[idx] = v;
    } else if (idx < 7168) {
        int r = idx - 4096;
        int lm = r >> 10, k = (r >> 5) & 31, j = r & 31;
        const float* W = Wih + lm * 4096;
        f4 v = { W[j*32+k], W[(j+32)*32+k], W[(j+64)*32+k], W[(j+96)*32+k] };
        wX[r] = v;
    } else if (idx < 7232) {
        int r = idx - 7168;
        int k = r >> 5, j = r & 31;                           // W_ih0 is (128,2)
        f4 v = { Wih0[j*2+k], Wih0[(j+32)*2+k], Wih0[(j+64)*2+k], Wih0[(j+96)*2+k] };
        wX0[r] = v;
    } else if (idx < 7360) {
        int r = idx - 7232;
        int l = r >> 5, j = r & 31;
        const float* bi = bih + l * 128;
        const float* bh = bhh + l * 128;
        f4 v = { bi[j]+bh[j], bi[j+32]+bh[j+32], bi[j+64]+bh[j+64], bi[j+96]+bh[j+96] };
        bs[r] = v;
    }
}

// block = 1 wave = 64 threads = 2 batch-quads x 32 hidden units. Each thread owns
// 4 batch rows of hidden unit j across all 4 layers. The h exchange (thread (bq,j)
// reads h written by thread (bq,k)) is entirely WITHIN the wave -> no s_barrier
// anywhere; ordering via s_waitcnt lgkmcnt(0) only, so global weight loads pipeline
// freely across layers and timesteps.
__global__ __launch_bounds__(64, 2)
void lstm_fused(const float* __restrict__ xg, const float* __restrict__ ws,
                const float* __restrict__ Wlin, const float* __restrict__ blin,
                float* __restrict__ out) {
    __shared__ float h_lds[4 * HLAY] __attribute__((aligned(16)));

    const int tid = threadIdx.x;
    const int j   = tid & 31;        // hidden unit
    const int bq  = tid >> 5;        // batch quad 0..1
    const int b0  = blockIdx.x * 8 + bq * 4;

    const f4* wH  = (const f4*)(ws + WH_OFF);
    const f4* wX  = (const f4*)(ws + WX_OFF);
    const f4* wX0 = (const f4*)(ws + WX0_OFF);
    const f4* bs  = (const f4*)(ws + BS_OFF);

    // zero h state (1024 floats = 256 f4, 4 per thread)
    {
        f4 z = {0.f, 0.f, 0.f, 0.f};
        ((f4*)h_lds)[tid]       = z;
        ((f4*)h_lds)[tid + 64]  = z;
        ((f4*)h_lds)[tid + 128] = z;
        ((f4*)h_lds)[tid + 192] = z;
    }

    // preload per-thread constants
    f4 bias_r[4];
#pragma unroll
    for (int l = 0; l < 4; ++l) bias_r[l] = bs[l * 32 + j];
    const f4 wx00 = wX0[j];
    const f4 wx01 = wX0[32 + j];

    float c_st[4][4];
#pragma unroll
    for (int l = 0; l < 4; ++l)
#pragma unroll
        for (int bb = 0; bb < 4; ++bb) c_st[l][bb] = 0.0f;

    const float* xb = xg + (size_t)b0 * 192;

    LGKM0();   // zeros visible to this wave's reads

    f4 acc[4];
    float hn[4];

    for (int t = 0; t < 64; ++t) {
        // ---------------- layer 0: input = x[b][0..1][t] ----------------
#pragma unroll
        for (int bb = 0; bb < 4; ++bb) {
            float x0 = xb[bb * 192 + t];
            float x1 = xb[bb * 192 + 64 + t];
            acc[bb] = bias_r[0] + wx00 * x0 + wx01 * x1;
        }
#pragma unroll 16
        for (int k = 0; k < 32; ++k) {
            f4 w = wH[k * 32 + j];
            f4 a = *(const f4*)&h_lds[k * HROW + bq * 4];
            acc[0] += w * a.x; acc[1] += w * a.y; acc[2] += w * a.z; acc[3] += w * a.w;
        }
#pragma unroll
        for (int bb = 0; bb < 4; ++bb) {
            float ig = fsig(acc[bb].x), fg = fsig(acc[bb].y);
            float gg = ftanh(acc[bb].z), og = fsig(acc[bb].w);
            float cn = fg * c_st[0][bb] + ig * gg;
            c_st[0][bb] = cn;
            hn[bb] = og * ftanh(cn);
        }
        {
            f4 v = { hn[0], hn[1], hn[2], hn[3] };
            *(f4*)&h_lds[j * HROW + bq * 4] = v;
        }
        LGKM0();   // h[0] write visible to this wave

        // ---------------- layers 1..3 ----------------
#pragma unroll
        for (int l = 1; l < 4; ++l) {
#pragma unroll
            for (int bb = 0; bb < 4; ++bb) acc[bb] = bias_r[l];
#pragma unroll 16
            for (int k = 0; k < 32; ++k) {   // input part: h of layer l-1 (this step)
                f4 w = wX[((l - 1) * 32 + k) * 32 + j];
                f4 a = *(const f4*)&h_lds[(l - 1) * HLAY + k * HROW + bq * 4];
                acc[0] += w * a.x; acc[1] += w * a.y; acc[2] += w * a.z; acc[3] += w * a.w;
            }
#pragma unroll 16
            for (int k = 0; k < 32; ++k) {   // recurrent part: h of layer l (prev step)
                f4 w = wH[(l * 32 + k) * 32 + j];
                f4 a = *(const f4*)&h_lds[l * HLAY + k * HROW + bq * 4];
                acc[0] += w * a.x; acc[1] += w * a.y; acc[2] += w * a.z; acc[3] += w * a.w;
            }
#pragma unroll
            for (int bb = 0; bb < 4; ++bb) {
                float ig = fsig(acc[bb].x), fg = fsig(acc[bb].y);
                float gg = ftanh(acc[bb].z), og = fsig(acc[bb].w);
                float cn = fg * c_st[l][bb] + ig * gg;
                c_st[l][bb] = cn;
                hn[bb] = og * ftanh(cn);
            }
            {
                f4 v = { hn[0], hn[1], hn[2], hn[3] };
                *(f4*)&h_lds[l * HLAY + j * HROW + bq * 4] = v;
            }
            LGKM0();   // h[l] write visible to this wave
        }
    }

    // ---------------- output head: sigmoid(h3 . W_lin + b_lin), wave-local ----------------
    if (tid < 8) {
        int row = tid;
        float s = blin[0];
#pragma unroll
        for (int k = 0; k < 32; ++k)
            s += Wlin[k] * h_lds[3 * HLAY + k * HROW + row];
        out[blockIdx.x * 8 + row] = fsig(s);
    }
}

extern "C" void kernel_launch(void* const* d_in, const int* in_sizes, int n_in,
                              void* d_out, int out_size, void* d_ws, size_t ws_size,
                              hipStream_t stream) {
    const float* x    = (const float*)d_in[0];
    const float* Wih0 = (const float*)d_in[1];
    const float* Wih  = (const float*)d_in[2];
    const float* Whh  = (const float*)d_in[3];
    const float* bih  = (const float*)d_in[4];
    const float* bhh  = (const float*)d_in[5];
    const float* Wlin = (const float*)d_in[6];
    const float* blin = (const float*)d_in[7];
    float* ws  = (float*)d_ws;
    float* out = (float*)d_out;

    pack_weights<<<29, 256, 0, stream>>>(Wih0, Wih, Whh, bih, bhh, ws);
    lstm_fused<<<2048, 64, 0, stream>>>(x, ws, Wlin, blin, out);
}

// Round 3
// 1620.756 us; speedup vs baseline: 1.1384x; 1.1126x over previous
//
#include <hip/hip_runtime.h>

typedef float f4 __attribute__((ext_vector_type(4)));

__device__ __forceinline__ float fsig(float x) {
    float e = __builtin_amdgcn_exp2f(x * -1.4426950408889634f);
    return __builtin_amdgcn_rcpf(1.0f + e);
}
__device__ __forceinline__ float ftanh(float x) {
    float e = __builtin_amdgcn_exp2f(x * -2.8853900817779268f); // e^{-2x}
    return 2.0f * __builtin_amdgcn_rcpf(1.0f + e) - 1.0f;
}

// ws layout:
//   W4[l][Jg][kp][jj][kk][g] : 4*8*32*4*2*4 = 32768 floats (128 KB)
//     l=layer, Jg=unit-group (j = Jg*4+jj), k = kp*2+kk, g = gate (i,f,g,o)
//     l==0: k<2 -> W_ih0 cols; k in [2,34) -> W_hh[0] col k-2; rest 0
//     l>=1: k<32 -> W_ih[l-1] col k;  k>=32 -> W_hh[l] col k-32
//   BS[l][j][g] at +32768 : 512 floats (bias b_ih+b_hh)
__global__ void pack_weights(const float* __restrict__ Wih0, const float* __restrict__ Wih,
                             const float* __restrict__ Whh,  const float* __restrict__ bih,
                             const float* __restrict__ bhh,  float* __restrict__ ws) {
    int idx = blockIdx.x * 256 + threadIdx.x;
    if (idx < 32768) {
        int g = idx & 3, k = (idx >> 2) & 63, j = (idx >> 8) & 31, l = idx >> 13;
        int row = g * 32 + j;                 // gate g of unit j = weight-matrix row
        float v = 0.0f;
        if (l == 0) {
            if (k < 2)       v = Wih0[row*2 + k];
            else if (k < 34) v = Whh[row*32 + (k-2)];
        } else {
            if (k < 32)      v = Wih[(l-1)*4096 + row*32 + k];
            else             v = Whh[l*4096 + row*32 + (k-32)];
        }
        int dst = ((((l*8 + (j>>2))*32 + (k>>1))*4 + (j&3))*2 + (k&1))*4 + g;
        ws[dst] = v;
    } else if (idx < 33280) {
        int r = idx - 32768;                  // l*128 + j*4 + g
        int g = r & 3, j = (r >> 2) & 31, l = r >> 7;
        int row = g*32 + j;
        ws[32768 + r] = bih[l*128 + row] + bhh[l*128 + row];
    }
}

#define EPI(A, L, JH, JJ) { \
    float ii = fsig((A).x), ff = fsig((A).y), gg = ftanh((A).z), oo = fsig((A).w); \
    float cn = ff * c[L][(JH)*4+(JJ)] + ii * gg; \
    c[L][(JH)*4+(JJ)] = cn; \
    hw[(Jg*4+(JJ))*64] = oo * ftanh(cn); }

// block = 256 threads = 4 waves. lane (0..63) = batch row; waves split the 32
// hidden units (8 each). Weights are wave-uniform -> s_load / SGPR operands.
// h exchanged via LDS [l][parity][k][lane] (stride-1, conflict-free).
__global__ __launch_bounds__(256, 1)
void lstm_fused(const float* __restrict__ xg, const float* __restrict__ ws,
                const float* __restrict__ Wlin, const float* __restrict__ blin,
                float* __restrict__ out) {
    __shared__ float hbuf[4*2*32*64];   // [l][p][k][lane]  64 KB
    const int tid  = threadIdx.x;
    const int lane = tid & 63;
    const int wv   = __builtin_amdgcn_readfirstlane(tid >> 6);  // uniform wave id
    const int row  = blockIdx.x * 64 + lane;

    const f4* W4 = (const f4*)ws;
    const f4* BS = (const f4*)(ws + 32768);

    // zero parity-0 h buffers (t=0 recurrent reads)
    for (int i = tid; i < 8192; i += 256) {
        int l = i >> 11, off = i & 2047;
        hbuf[l*4096 + off] = 0.0f;
    }

    float c[4][8];
#pragma unroll
    for (int l = 0; l < 4; ++l)
#pragma unroll
        for (int u = 0; u < 8; ++u) c[l][u] = 0.0f;

    const float* xr = xg + (size_t)row * 192;
    float xc0 = xr[0], xc1 = xr[64];

    __syncthreads();

    for (int t = 0; t < 64; ++t) {
        const int prevp = t & 1;
        const int curp  = prevp ^ 1;
        const int tn = (t < 63) ? (t + 1) : 63;
        float xn0 = xr[tn], xn1 = xr[64 + tn];   // prefetch next-t x

        // ---------------- layer 0 ----------------
#pragma unroll
        for (int jh = 0; jh < 2; ++jh) {
            const int Jg = wv*2 + jh;                      // uniform
            const f4* wb = W4 + Jg*256;                    // l=0 block
            const f4* bp = BS + Jg*4;
            f4 a0 = bp[0], a1 = bp[1], a2 = bp[2], a3 = bp[3];
            a0 += wb[0]*xc0; a0 += wb[1]*xc1;
            a1 += wb[2]*xc0; a1 += wb[3]*xc1;
            a2 += wb[4]*xc0; a2 += wb[5]*xc1;
            a3 += wb[6]*xc0; a3 += wb[7]*xc1;
            const float* hr = &hbuf[prevp*2048 + lane];
#pragma unroll 2
            for (int kp = 0; kp < 16; ++kp) {
                float h0 = hr[kp*128], h1 = hr[kp*128 + 64];
                const f4* w = wb + 8 + kp*8;
                a0 += w[0]*h0; a0 += w[1]*h1;
                a1 += w[2]*h0; a1 += w[3]*h1;
                a2 += w[4]*h0; a2 += w[5]*h1;
                a3 += w[6]*h0; a3 += w[7]*h1;
            }
            float* hw = &hbuf[curp*2048 + lane];
            EPI(a0, 0, jh, 0) EPI(a1, 0, jh, 1) EPI(a2, 0, jh, 2) EPI(a3, 0, jh, 3)
        }
        __syncthreads();

        // ---------------- layers 1..3 ----------------
#pragma unroll
        for (int l = 1; l < 4; ++l) {
#pragma unroll
            for (int jh = 0; jh < 2; ++jh) {
                const int Jg = wv*2 + jh;
                const f4* wb = W4 + (l*8 + Jg)*256;
                const f4* bp = BS + l*32 + Jg*4;
                f4 a0 = bp[0], a1 = bp[1], a2 = bp[2], a3 = bp[3];
                const float* hi = &hbuf[((l-1)*2 + curp)*2048 + lane];
                const float* hr = &hbuf[(l*2 + prevp)*2048 + lane];
#pragma unroll 2
                for (int kp = 0; kp < 16; ++kp) {          // input part (h of l-1, time t)
                    float h0 = hi[kp*128], h1 = hi[kp*128 + 64];
                    const f4* w = wb + kp*8;
                    a0 += w[0]*h0; a0 += w[1]*h1;
                    a1 += w[2]*h0; a1 += w[3]*h1;
                    a2 += w[4]*h0; a2 += w[5]*h1;
                    a3 += w[6]*h0; a3 += w[7]*h1;
                }
#pragma unroll 2
                for (int kp = 0; kp < 16; ++kp) {          // recurrent part (h of l, t-1)
                    float h0 = hr[kp*128], h1 = hr[kp*128 + 64];
                    const f4* w = wb + 128 + kp*8;
                    a0 += w[0]*h0; a0 += w[1]*h1;
                    a1 += w[2]*h0; a1 += w[3]*h1;
                    a2 += w[4]*h0; a2 += w[5]*h1;
                    a3 += w[6]*h0; a3 += w[7]*h1;
                }
                float* hw = &hbuf[(l*2 + curp)*2048 + lane];
                EPI(a0, l, jh, 0) EPI(a1, l, jh, 1) EPI(a2, l, jh, 2) EPI(a3, l, jh, 3)
            }
            __syncthreads();
        }

        xc0 = xn0; xc1 = xn1;
    }

    // ---------------- output head ----------------
    // final t=63: curp = 0 -> h3 at parity 0
    if (tid < 64) {
        const float* h3 = &hbuf[3*4096 + lane];
        float s = blin[0];
        for (int k = 0; k < 32; ++k)
            s += Wlin[k] * h3[k*64];
        out[row] = fsig(s);
    }
}

extern "C" void kernel_launch(void* const* d_in, const int* in_sizes, int n_in,
                              void* d_out, int out_size, void* d_ws, size_t ws_size,
                              hipStream_t stream) {
    const float* x    = (const float*)d_in[0];
    const float* Wih0 = (const float*)d_in[1];
    const float* Wih  = (const float*)d_in[2];
    const float* Whh  = (const float*)d_in[3];
    const float* bih  = (const float*)d_in[4];
    const float* bhh  = (const float*)d_in[5];
    const float* Wlin = (const float*)d_in[6];
    const float* blin = (const float*)d_in[7];
    float* ws  = (float*)d_ws;
    float* out = (float*)d_out;

    pack_weights<<<130, 256, 0, stream>>>(Wih0, Wih, Whh, bih, bhh, ws);
    lstm_fused<<<256, 256, 0, stream>>>(x, ws, Wlin, blin, out);
}